// Round 5
// baseline (327.101 us; speedup 1.0000x reference)
//
#include <hip/hip_runtime.h>
#include <stdint.h>

typedef _Float16 f16;
typedef f16 f16x8 __attribute__((ext_vector_type(8)));
typedef float f32x4 __attribute__((ext_vector_type(4)));

#define MFMA(a,b,c) __builtin_amdgcn_mfma_f32_16x16x32_f16(a, b, c, 0, 0, 0)

__device__ __forceinline__ float sigmoidf_(float z) { return 1.0f / (1.0f + __expf(-z)); }

typedef const __attribute__((address_space(1))) uint32_t glob_u32;
typedef __attribute__((address_space(3))) uint32_t lds_u32;
__device__ __forceinline__ void async_ld16(const float* g, void* l) {
  __builtin_amdgcn_global_load_lds((glob_u32*)g, (lds_u32*)l, 16, 0, 0);
}

// ---------------------------------------------------------------------------
// prep: scale[b]; weights -> f16; zero out[0..63] and flags.
// Wopt: fragment-permuted [Aq;Ak;Av] (192x2048):
//   (r,k) -> ((rt*64+kc)*16+(r&15))*32 + ((k>>3)&3)*8 + (k&7), rt=r>>4, kc=k>>5
// Wsm = 9 x (64x64): Aq1,Ak1,Av1,Aq5,Ak5,Av5,Ao,Ao1,Ao5
// ---------------------------------------------------------------------------
__global__ void prep_kernel(const float* __restrict__ L,
    const float* __restrict__ Aq, const float* __restrict__ Ak, const float* __restrict__ Av,
    const float* __restrict__ Aq1, const float* __restrict__ Ak1, const float* __restrict__ Av1,
    const float* __restrict__ Aq5, const float* __restrict__ Ak5, const float* __restrict__ Av5,
    const float* __restrict__ Ao, const float* __restrict__ Ao1, const float* __restrict__ Ao5,
    float* __restrict__ scale, f16* __restrict__ Wopt, f16* __restrict__ Wsm,
    float* __restrict__ out, unsigned int* __restrict__ flagg)
{
  __shared__ float r4[4];
  int blk = blockIdx.x, t = threadIdx.x;
  if (blk < 64) {
    float v = (L[blk * 512 + t] >= 1.0f) ? 1.0f : 0.0f;
    #pragma unroll
    for (int off = 32; off; off >>= 1) v += __shfl_down(v, off);
    if ((t & 63) == 0) r4[t >> 6] = v;
    __syncthreads();
    if (t == 0) scale[blk] = sqrtf(r4[0] + r4[1] + r4[2] + r4[3] + 1.0f);
  } else if (blk < 160) {
    int base = (blk - 64) * 4096;
    for (int i = 0; i < 16; i++) {
      int idx = base + t + i * 256;
      int r = idx >> 11, k = idx & 2047;
      float v = (r < 64) ? Aq[r * 2048 + k]
              : (r < 128) ? Ak[(r - 64) * 2048 + k]
              : Av[(r - 128) * 2048 + k];
      int rt = r >> 4, lr = r & 15, kc = k >> 5, qq = (k >> 3) & 3, jj = k & 7;
      Wopt[((rt * 64 + kc) * 16 + lr) * 32 + qq * 8 + jj] = (f16)v;
    }
  } else if (blk < 169) {
    int j = blk - 160;
    const float* s = (j == 0) ? Aq1 : (j == 1) ? Ak1 : (j == 2) ? Av1 : (j == 3) ? Aq5
                   : (j == 4) ? Ak5 : (j == 5) ? Av5 : (j == 6) ? Ao : (j == 7) ? Ao1 : Ao5;
    for (int i = 0; i < 16; i++) { int idx = t + i * 256; Wsm[j * 4096 + idx] = (f16)s[idx]; }
  } else {
    if (t < 64) out[t] = 0.0f;
    else if (t < 128) flagg[t - 64] = 0u;
  }
}

// ---------------------------------------------------------------------------
// fused: phase A = qkv for n-slice 64 (producer/consumer waves, async LDS
// staging); per-batch flag barrier; phase B = 3-layer attn chain (R3 body).
// grid (4,64), 512 threads, 133120 B LDS -> 1 block/CU, 256 co-resident.
// ---------------------------------------------------------------------------
__global__ __launch_bounds__(512) void fused_kernel(const float* __restrict__ x,
    const float* __restrict__ scale, const f16* __restrict__ Wopt,
    const f16* __restrict__ Wsm, f16* __restrict__ Ktg, f16* __restrict__ Vgg,
    f16* __restrict__ MA, f16* __restrict__ MB,
    unsigned int* __restrict__ flagg, float* __restrict__ out)
{
  int g = blockIdx.x, b = blockIdx.y, n0 = g * 64;
  int t = threadIdx.x, lane = t & 63, w = t >> 6;
  int l15 = lane & 15, q = lane >> 4;

  __shared__ __align__(16) char smem[133120];
  // phase A views: XB[p] = smem + p*66560, fp32 [f][64] in 4-row groups of
  // 1040 B (1024 data + 16 pad)
  // phase B views:
  f16* KT = (f16*)(smem);             // [256][72]
  f16* SM = (f16*)(smem + 36864);     // [256][72] / S as [64][264]
  f16* VM = (f16*)(smem + 73728);     // [64][264]
  f16* QT = (f16*)(smem + 107520);    // [64][72]  (later Mst [64][64])
  f16* OT = (f16*)(smem + 116736);    // [64][72]
  float* denomS = (float*)(smem + 125952);  // [64]

  float sinv = 1.0f / scale[b];

  // ========================== PHASE A: qkv ==========================
  {
    const float* xb = x + (size_t)b * 524288 + n0;
    bool producer = (w < 4);
    int lr = lane >> 4, lc = (lane & 15) * 4;

    f32x4 acc[4][3] = {};
    int rt0 = (w - 4) * 3;  // consumer r-tiles (valid for w>=4)

    auto prefetchChunk = [&](int c, int p) {
      char* bb = smem + p * 66560;
      #pragma unroll
      for (int s = 0; s < 16; s++) {
        int grp = w * 16 + s;
        int f = c * 256 + grp * 4 + lr;
        async_ld16(xb + (size_t)f * 256 + lc, bb + grp * 1040);
      }
    };
    auto computeChunk = [&](int c, int p) {
      const char* bb = smem + p * 66560;
      #pragma unroll
      for (int kk = 0; kk < 8; kk++) {
        f16x8 af[4];
        #pragma unroll
        for (int nt = 0; nt < 4; nt++) {
          const char* rb = bb + (size_t)(kk * 8 + q * 2) * 1040
                         + (size_t)(nt * 16 + l15) * 4;
          #pragma unroll
          for (int j = 0; j < 8; j++)
            af[nt][j] = (f16)(*(const float*)(rb + (j >> 2) * 1040 + (j & 3) * 256));
        }
        int kc = c * 8 + kk;
        #pragma unroll
        for (int j = 0; j < 3; j++) {
          f16x8 bf = *(const f16x8*)(Wopt
              + ((size_t)((rt0 + j) * 64 + kc) * 16 + l15) * 32 + q * 8);
          #pragma unroll
          for (int nt = 0; nt < 4; nt++)
            acc[nt][j] = MFMA(af[nt], bf, acc[nt][j]);
        }
      }
    };

    if (producer) prefetchChunk(0, 0);
    __syncthreads();
    for (int c = 0; c < 8; c++) {
      if (producer) { if (c < 7) prefetchChunk(c + 1, (c + 1) & 1); }
      else computeChunk(c, c & 1);
      __syncthreads();
    }

    // consumer epilogue: sigmoid; Q -> LDS QT, K/V -> global
    if (!producer) {
      #pragma unroll
      for (int nt = 0; nt < 4; nt++)
        #pragma unroll
        for (int j = 0; j < 3; j++) {
          int rr = (rt0 + j) * 16 + l15;
          float s[4];
          #pragma unroll
          for (int reg = 0; reg < 4; reg++) s[reg] = sigmoidf_(acc[nt][j][reg]);
          int nl = nt * 16 + q * 4;
          if (rr < 64) {
            #pragma unroll
            for (int reg = 0; reg < 4; reg++)
              QT[(nl + reg) * 72 + rr] = (f16)s[reg];
          } else if (rr < 128) {
            #pragma unroll
            for (int reg = 0; reg < 4; reg++)
              Ktg[(size_t)b * 16384 + (size_t)(n0 + nl + reg) * 64 + (rr - 64)] = (f16)s[reg];
          } else {
            union { f16 h[4]; uint2 u; } pk;
            #pragma unroll
            for (int reg = 0; reg < 4; reg++) pk.h[reg] = (f16)s[reg];
            *(uint2*)(Vgg + (size_t)b * 16384 + (size_t)(rr - 128) * 256 + (n0 + nl)) = pk.u;
          }
        }
    }
    __syncthreads();
    if (t == 0) {
      __threadfence();
      atomicAdd(&flagg[b], 1u);
      while (__hip_atomic_load(&flagg[b], __ATOMIC_ACQUIRE, __HIP_MEMORY_SCOPE_AGENT) < 4u)
        __builtin_amdgcn_s_sleep(2);
      __threadfence();
    }
    __syncthreads();
  }

  // ========================== PHASE B: attn ==========================
  #pragma unroll 1
  for (int l = 0; l < 3; l++) {
    if (t < 64) denomS[t] = 0.0f;

    const f16* Wq = Wsm + (size_t)(l == 1 ? 0 : 3) * 4096;
    const f16* Wk = Wsm + (size_t)(l == 1 ? 1 : 4) * 4096;
    const f16* Wv = Wsm + (size_t)(l == 1 ? 2 : 5) * 4096;
    const f16* Wo = Wsm + (size_t)(l == 0 ? 6 : (l == 1 ? 7 : 8)) * 4096;

    if (l == 0) {
      // KT/VM from global (Q already local in QT)
      const uint4* ks = (const uint4*)(Ktg + (size_t)b * 16384);
      const uint4* vs = (const uint4*)(Vgg + (size_t)b * 16384);
      #pragma unroll
      for (int i = 0; i < 4; i++) {
        int id = t + i * 512;
        int m = id >> 3, c = id & 7;
        *(uint4*)&KT[m * 72 + c * 8] = ks[id];
        int r = id >> 5, c2 = id & 31;
        *(uint4*)&VM[r * 264 + c2 * 8] = vs[id];
      }
      __syncthreads();
    } else {
      const f16* Min = (l == 1) ? MA : MB;
      const uint4* ms = (const uint4*)(Min + (size_t)b * 16384);
      #pragma unroll
      for (int i = 0; i < 4; i++) {
        int id = t + i * 512, m = id >> 3, c = id & 7;
        *(uint4*)&SM[m * 72 + c * 8] = ms[id];
      }
      __syncthreads();
      if (w < 4) {
        // KT[m][r] = sigmoid( sum_s M^T[m][s] * Wk[r][s] )
        f16x8 bk[4][2];
        #pragma unroll
        for (int rt = 0; rt < 4; rt++) {
          bk[rt][0] = *(const f16x8*)(Wk + (rt * 16 + l15) * 64 + q * 8);
          bk[rt][1] = *(const f16x8*)(Wk + (rt * 16 + l15) * 64 + 32 + q * 8);
        }
        #pragma unroll
        for (int mi = 0; mi < 4; mi++) {
          int mt = w * 4 + mi;
          f16x8 a0 = *(const f16x8*)&SM[(mt * 16 + l15) * 72 + q * 8];
          f16x8 a1 = *(const f16x8*)&SM[(mt * 16 + l15) * 72 + 32 + q * 8];
          #pragma unroll
          for (int rt = 0; rt < 4; rt++) {
            f32x4 acc = {}; acc = MFMA(a0, bk[rt][0], acc); acc = MFMA(a1, bk[rt][1], acc);
            #pragma unroll
            for (int reg = 0; reg < 4; reg++)
              KT[(mt * 16 + q * 4 + reg) * 72 + rt * 16 + l15] = (f16)sigmoidf_(acc[reg]);
          }
        }
      } else {
        // VM[r][m] = sigmoid( sum_s Wv[r][s] * M^T[m][s] )
        f16x8 av[4][2];
        #pragma unroll
        for (int rt = 0; rt < 4; rt++) {
          av[rt][0] = *(const f16x8*)(Wv + (rt * 16 + l15) * 64 + q * 8);
          av[rt][1] = *(const f16x8*)(Wv + (rt * 16 + l15) * 64 + 32 + q * 8);
        }
        #pragma unroll
        for (int mi = 0; mi < 4; mi++) {
          int mt = (w - 4) * 4 + mi;
          f16x8 b0 = *(const f16x8*)&SM[(mt * 16 + l15) * 72 + q * 8];
          f16x8 b1 = *(const f16x8*)&SM[(mt * 16 + l15) * 72 + 32 + q * 8];
          #pragma unroll
          for (int rt = 0; rt < 4; rt++) {
            f32x4 acc = {}; acc = MFMA(av[rt][0], b0, acc); acc = MFMA(av[rt][1], b1, acc);
            #pragma unroll
            for (int reg = 0; reg < 4; reg++)
              VM[(rt * 16 + q * 4 + reg) * 264 + mt * 16 + l15] = (f16)sigmoidf_(acc[reg]);
          }
        }
      }
      // QT for local rows
      {
        int nt = w >> 1;
        f16x8 a0 = *(const f16x8*)&SM[(n0 + nt * 16 + l15) * 72 + q * 8];
        f16x8 a1 = *(const f16x8*)&SM[(n0 + nt * 16 + l15) * 72 + 32 + q * 8];
        #pragma unroll
        for (int j = 0; j < 2; j++) {
          int rt = (w & 1) * 2 + j;
          f16x8 b0 = *(const f16x8*)(Wq + (rt * 16 + l15) * 64 + q * 8);
          f16x8 b1 = *(const f16x8*)(Wq + (rt * 16 + l15) * 64 + 32 + q * 8);
          f32x4 acc = {}; acc = MFMA(a0, b0, acc); acc = MFMA(a1, b1, acc);
          #pragma unroll
          for (int reg = 0; reg < 4; reg++)
            QT[(nt * 16 + q * 4 + reg) * 72 + rt * 16 + l15] = (f16)sigmoidf_(acc[reg]);
        }
      }
      __syncthreads();
    }

    // S = exp(QK^T * sinv) -> SM as [64][264]; denom via shfl + LDS atomic
    {
      int nt = w >> 1;
      f16x8 a0 = *(const f16x8*)&QT[(nt * 16 + l15) * 72 + q * 8];
      f16x8 a1 = *(const f16x8*)&QT[(nt * 16 + l15) * 72 + 32 + q * 8];
      float dsum[4] = {0.f, 0.f, 0.f, 0.f};
      #pragma unroll
      for (int mi = 0; mi < 8; mi++) {
        int mt = (w & 1) * 8 + mi;
        f16x8 b0 = *(const f16x8*)&KT[(mt * 16 + l15) * 72 + q * 8];
        f16x8 b1 = *(const f16x8*)&KT[(mt * 16 + l15) * 72 + 32 + q * 8];
        f32x4 acc = {}; acc = MFMA(a0, b0, acc); acc = MFMA(a1, b1, acc);
        #pragma unroll
        for (int reg = 0; reg < 4; reg++) {
          float e = __expf(acc[reg] * sinv);
          dsum[reg] += e;
          SM[(nt * 16 + q * 4 + reg) * 264 + mt * 16 + l15] = (f16)e;
        }
      }
      #pragma unroll
      for (int reg = 0; reg < 4; reg++) {
        #pragma unroll
        for (int mask = 1; mask < 16; mask <<= 1) dsum[reg] += __shfl_xor(dsum[reg], mask);
      }
      if (l15 == 0) {
        #pragma unroll
        for (int reg = 0; reg < 4; reg++) atomicAdd(&denomS[nt * 16 + q * 4 + reg], dsum[reg]);
      }
    }
    __syncthreads();

    // AV: o^T[n][r] = sum_m S[n][m] VM[r][m]; normalize -> OT
    {
      int nt = w >> 1;
      f32x4 oacc[2] = {};
      #pragma unroll
      for (int kc = 0; kc < 8; kc++) {
        f16x8 af = *(const f16x8*)&SM[(nt * 16 + l15) * 264 + kc * 32 + q * 8];
        #pragma unroll
        for (int j = 0; j < 2; j++) {
          int rt = (w & 1) * 2 + j;
          f16x8 bf = *(const f16x8*)&VM[(rt * 16 + l15) * 264 + kc * 32 + q * 8];
          oacc[j] = MFMA(af, bf, oacc[j]);
        }
      }
      #pragma unroll
      for (int j = 0; j < 2; j++) {
        int rt = (w & 1) * 2 + j;
        #pragma unroll
        for (int reg = 0; reg < 4; reg++) {
          int row = nt * 16 + q * 4 + reg;
          OT[row * 72 + rt * 16 + l15] = (f16)(oacc[j][reg] / denomS[row]);
        }
      }
    }
    __syncthreads();

    // M'[n][s] = silu( sum_r OT[n][r] Wo[s][r] ) -> Mst (QT reused, stride 64)
    f16* Mst = QT;
    {
      int nt = w >> 1;
      f16x8 a0 = *(const f16x8*)&OT[(nt * 16 + l15) * 72 + q * 8];
      f16x8 a1 = *(const f16x8*)&OT[(nt * 16 + l15) * 72 + 32 + q * 8];
      #pragma unroll
      for (int j = 0; j < 2; j++) {
        int st = (w & 1) * 2 + j;
        f16x8 b0 = *(const f16x8*)(Wo + (st * 16 + l15) * 64 + q * 8);
        f16x8 b1 = *(const f16x8*)(Wo + (st * 16 + l15) * 64 + 32 + q * 8);
        f32x4 acc = {}; acc = MFMA(a0, b0, acc); acc = MFMA(a1, b1, acc);
        #pragma unroll
        for (int reg = 0; reg < 4; reg++) {
          float z = acc[reg];
          Mst[(nt * 16 + q * 4 + reg) * 64 + st * 16 + l15] = (f16)(z * sigmoidf_(z));
        }
      }
    }
    __syncthreads();

    if (l < 2) {
      f16* Mout = (l == 0) ? MA : MB;
      int row = t >> 3, c = t & 7;
      *(uint4*)(Mout + (size_t)b * 16384 + (size_t)(n0 + row) * 64 + c * 8)
          = *(const uint4*)&Mst[row * 64 + c * 8];
      if (t == 0) {
        __threadfence();
        atomicAdd(&flagg[b], 1u);
        unsigned int target = 4u * (unsigned)(l + 2);
        while (__hip_atomic_load(&flagg[b], __ATOMIC_ACQUIRE, __HIP_MEMORY_SCOPE_AGENT) < target)
          __builtin_amdgcn_s_sleep(2);
        __threadfence();
      }
      __syncthreads();
    } else {
      float contrib = 0.0f;
      if (t < 64) {
        int ntok = n0 + t;
        const f16* row = &Mst[t * 64];
        float d[4] = {0, 0, 0, 0}, pp = 0.0f;
        #pragma unroll
        for (int gg = 0; gg < 8; gg++) {
          f16x8 v = *(const f16x8*)(row + gg * 8);
          float ss = 0.0f;
          #pragma unroll
          for (int k = 0; k < 8; k++) { float f = (float)v[k]; ss += f * f; }
          if (gg < 4) d[gg] = ss; else pp += ss;
        }
        int np = ntok >> 1, c0 = (ntok & 1) * 2;
        const float* xb = x + (size_t)b * 524288 + (size_t)c0 * 256;
        float q1a = xb[np], q1b = xb[256 + np];
        float q2a = xb[128 + np], q2b = xb[384 + np];
        contrib = d[0] * (q1a * q1a + q1b * q1b)
                + (d[1] + d[2]) * (q1a * q2a + q1b * q2b)
                + d[3] * (q2a * q2a + q2b * q2b) + pp;
      }
      if (w == 0) {
        #pragma unroll
        for (int off = 32; off; off >>= 1) contrib += __shfl_down(contrib, off);
        if (lane == 0) atomicAdd(out + b, contrib);
      }
    }
  }
}

// ---------------------------------------------------------------------------
extern "C" void kernel_launch(void* const* d_in, const int* in_sizes, int n_in,
                              void* d_out, int out_size, void* d_ws, size_t ws_size,
                              hipStream_t stream) {
  const float* x   = (const float*)d_in[0];
  const float* L   = (const float*)d_in[1];
  const float* Aq  = (const float*)d_in[2];
  const float* Ak  = (const float*)d_in[3];
  const float* Av  = (const float*)d_in[4];
  const float* Aq1 = (const float*)d_in[5];
  const float* Ak1 = (const float*)d_in[6];
  const float* Av1 = (const float*)d_in[7];
  const float* Aq5 = (const float*)d_in[8];
  const float* Ak5 = (const float*)d_in[9];
  const float* Av5 = (const float*)d_in[10];
  const float* Ao  = (const float*)d_in[11];
  const float* Ao1 = (const float*)d_in[12];
  const float* Ao5 = (const float*)d_in[13];

  char* ws = (char*)d_ws;
  float* scale = (float*)ws;                              // 256 B
  f16* Wopt  = (f16*)(ws + 256);                          // 786432 B
  f16* Wsm   = (f16*)(ws + 786688);                       // 73728 B
  f16* Ktg   = (f16*)(ws + 860416);                       // 2 MB
  f16* Vgg   = (f16*)(ws + 2957568);                      // 2 MB
  f16* MbufA = (f16*)(ws + 5054720);                      // 2 MB
  f16* MbufB = (f16*)(ws + 7151872);                      // 2 MB
  unsigned int* flagg = (unsigned int*)(ws + 9249024);    // 256 B
  float* out = (float*)d_out;

  prep_kernel<<<170, 256, 0, stream>>>(L, Aq, Ak, Av, Aq1, Ak1, Av1,
                                       Aq5, Ak5, Av5, Ao, Ao1, Ao5,
                                       scale, Wopt, Wsm, out, flagg);
  fused_kernel<<<dim3(4, 64), 512, 0, stream>>>(x, scale, Wopt, Wsm,
                                                Ktg, Vgg, MbufA, MbufB, flagg, out);
}